// Round 4
// baseline (100.587 us; speedup 1.0000x reference)
//
#include <hip/hip_runtime.h>
#include <hip/hip_bf16.h>

#define BB 4
#define IN_DIM 8
#define OUT_DIM 64
#define N_WIN 64
#define N_SEQ 4096
#define N_REAL 6144

#define OG 8                       // output channels per block
#define TTILE 256                  // t positions per block
#define ZROWS (TTILE + N_WIN - 1)  // 319 rows incl. halo
#define ZPAD 9                     // row stride: gcd(9,32)=1 -> conflict-free

__global__ __launch_bounds__(64)
void astrf_fused(const float* __restrict__ x,
                 const float* __restrict__ w,
                 const float* __restrict__ bias,
                 const int* __restrict__ sidx,
                 float* __restrict__ out)
{
    __shared__ float zsh[ZROWS * ZPAD];          // [row][i], row = t' - (t0-63)
    __shared__ float wsh[IN_DIM * N_WIN * OG];   // [i][l][o]

    const int tid = threadIdx.x;
    const int t0  = blockIdx.x * TTILE;
    const int o0  = blockIdx.y * OG;
    const int b   = blockIdx.z;

    // ---- zero the scatter timeline ----
    for (int k = tid; k < ZROWS * ZPAD; k += 64) zsh[k] = 0.f;

    // ---- stage weights transposed: w[o][i][l] -> wsh[i][l][o] ----
    for (int k = tid; k < OG * IN_DIM * N_WIN; k += 64) {
        int o   = k >> 9;          // / (IN_DIM*N_WIN)
        int rem = k & 511;
        int i   = rem >> 6;        // / N_WIN
        int l   = rem & 63;
        wsh[(i * N_WIN + l) * OG + o] =
            w[((size_t)(o0 + o) * IN_DIM + i) * N_WIN + l];
    }

    __syncthreads();

    // ---- contributing source range: idx in [t0-63, t0+TTILE) ----
    const int* idxb = sidx + b * N_SEQ;
    const int vlo = t0 - (N_WIN - 1);
    const int vhi = t0 + TTILE;
    int lo = 0, hi = N_SEQ;
    while (lo < hi) { int m = (lo + hi) >> 1; if (idxb[m] < vlo) lo = m + 1; else hi = m; }
    const int slo = lo;
    hi = N_SEQ;
    while (lo < hi) { int m = (lo + hi) >> 1; if (idxb[m] < vhi) lo = m + 1; else hi = m; }
    const int shi = lo;

    // ---- scatter x[b,:,s] into LDS timeline (idx unique per batch) ----
    for (int s = slo + tid; s < shi; s += 64) {
        int r = idxb[s] - vlo;                       // [0, ZROWS)
        const float* xp = x + (size_t)b * IN_DIM * N_SEQ + s;
        #pragma unroll
        for (int i = 0; i < IN_DIM; ++i)
            zsh[r * ZPAD + i] = xp[(size_t)i * N_SEQ];
    }

    __syncthreads();

    // ---- dense correlation: lane owns t = t0 + tt*64 + tid ----
    float acc[4][OG];
    #pragma unroll
    for (int tt = 0; tt < 4; ++tt)
        #pragma unroll
        for (int o = 0; o < OG; ++o) acc[tt][o] = 0.f;

    #pragma unroll 2
    for (int l = 0; l < N_WIN; ++l) {
        #pragma unroll
        for (int i = 0; i < IN_DIM; ++i) {
            const float4 wa = *(const float4*)&wsh[(i * N_WIN + l) * OG + 0];
            const float4 wb = *(const float4*)&wsh[(i * N_WIN + l) * OG + 4];
            #pragma unroll
            for (int tt = 0; tt < 4; ++tt) {
                float zv = zsh[(tt * 64 + tid + (N_WIN - 1) - l) * ZPAD + i];
                acc[tt][0] += wa.x * zv;
                acc[tt][1] += wa.y * zv;
                acc[tt][2] += wa.z * zv;
                acc[tt][3] += wa.w * zv;
                acc[tt][4] += wb.x * zv;
                acc[tt][5] += wb.y * zv;
                acc[tt][6] += wb.z * zv;
                acc[tt][7] += wb.w * zv;
            }
        }
    }

    // ---- epilogue: bias + fp32 store (lanes consecutive in t: coalesced) ----
    #pragma unroll
    for (int o = 0; o < OG; ++o) {
        float bv = bias[o0 + o];
        #pragma unroll
        for (int tt = 0; tt < 4; ++tt) {
            int t = t0 + tt * 64 + tid;
            out[((size_t)b * OUT_DIM + o0 + o) * N_REAL + t] = acc[tt][o] + bv;
        }
    }
}

extern "C" void kernel_launch(void* const* d_in, const int* in_sizes, int n_in,
                              void* d_out, int out_size, void* d_ws, size_t ws_size,
                              hipStream_t stream) {
    const float* px = nullptr; const float* pw = nullptr;
    const float* pb = nullptr; const int* ps = nullptr;

    for (int i = 0; i < n_in; ++i) {
        switch (in_sizes[i]) {
            case BB * IN_DIM * N_SEQ:        px = (const float*)d_in[i]; break; // 131072 x
            case OUT_DIM * IN_DIM * N_WIN:   pw = (const float*)d_in[i]; break; // 32768 weight
            case OUT_DIM:                    pb = (const float*)d_in[i]; break; // 64 bias
            case BB * N_SEQ:                 ps = (const int*)d_in[i];   break; // 16384 idx
            default: break;                                                      // nRealLen etc.
        }
    }
    if (!px || !pw || !pb || !ps) {  // fall back to dict order (shouldn't happen)
        px = (const float*)d_in[0]; pw = (const float*)d_in[1];
        pb = (const float*)d_in[2]; ps = (const int*)d_in[3];
    }

    float* out = (float*)d_out;
    dim3 grid(N_REAL / TTILE, OUT_DIM / OG, BB);  // 24 x 8 x 4 = 768 blocks
    astrf_fused<<<grid, dim3(64), 0, stream>>>(px, pw, pb, ps, out);
}